// Round 18
// baseline (86.411 us; speedup 1.0000x reference)
//
#include <hip/hip_runtime.h>
#include <hip/hip_bf16.h>

// ModConv2d: per-sample modulated 3x3 conv (N=8, C=64->64, 256x256) + MLPs.
// Kernel 1: MLPs -> w_bf[n][kidx][cb][cout][8ci] (bf16, A-frag 16B units) + bias.
// Kernel 2 (R18 = R17 + nontemporal stores): implicit-GEMM conv,
//   builtin mfma_f32_32x32x16_bf16, 8-ci chunks, kidx-pair K=16 steps.
//   Block 512 thr (8 waves) = 4 output rows x 256 cols x 64 couts; wave
//   (wr, wh) = row x 128-col half; acc[2][4] = 128 AGPR; r/m = 0.75.
//   Grid 512. LDS = x [6 rows][258][16B] dbuf (49.5 KB) + weights once
//   (73.7 KB) = 123.3 KB, 1 block/CU, 2 waves/SIMD.
//   Staging: thread owns col w, rows {r0, r0+2, r0+4}; depth-1 ISSUE s0-2 /
//   WRITE s3-4. Raw s_barrier + lgkmcnt(0); setprio on MFMA cluster; cvtpk.
//   NEW: epilogue stores are NONTEMPORAL — out is write-once/never-read;
//   keeping it out of L2 preserves x/weight residency for neighbor blocks
//   on the same XCD (12.6 MB working set vs 4 MB L2).

typedef short bf16x8 __attribute__((ext_vector_type(8)));
typedef float f32x16 __attribute__((ext_vector_type(16)));

#define NB 8
#define CIN 64
#define COUT 64
#define HH 256
#define WW 256
#define HWP (HH * WW)
#define AUXD 128
#define HIDD 256

#define XRW8 (258 * 16)            // 4128 B: one staged row-plane (8 ci)
#define XBUF6 (6 * XRW8)           // 24768 B per buffer
#define WOFF6 (2 * XBUF6)          // 49536
#define WUNITS (9 * 8 * 64)        // 4608 16B units
#define SMEMB6 (WOFF6 + (WUNITS + 1) * 16)  // 123280

__device__ __forceinline__ unsigned short f2bf(float f) {
    unsigned u = __builtin_bit_cast(unsigned, f);
    u += 0x7FFFu + ((u >> 16) & 1u);   // RNE
    return (unsigned short)(u >> 16);
}

__device__ __forceinline__ unsigned cvtpk(float a, float b) {
    unsigned r;  // r[15:0] = bf16(a), r[31:16] = bf16(b)
    asm volatile("v_cvt_pk_bf16_f32 %0, %1, %2" : "=v"(r) : "v"(a), "v"(b));
    return r;
}

// ---------------- Kernel 1: MLPs ----------------
__global__ __launch_bounds__(256) void mlp_kernel(
    const float* __restrict__ y, const float* __restrict__ weight,
    const float* __restrict__ fc_w1, const float* __restrict__ fc_b1,
    const float* __restrict__ fc_prelu,
    const float* __restrict__ fc_w2, const float* __restrict__ fc_b2,
    const float* __restrict__ bias_w1, const float* __restrict__ bias_b1,
    const float* __restrict__ bias_prelu,
    const float* __restrict__ bias_w2, const float* __restrict__ bias_b2,
    unsigned short* __restrict__ w_bf, float* __restrict__ bvec)
{
    const int n = blockIdx.y;
    const int c = blockIdx.x;
    const int tid = threadIdx.x;
    __shared__ float ylds[AUXD];
    __shared__ float hl[HIDD];
    if (tid < AUXD) ylds[tid] = y[n * AUXD + tid];
    __syncthreads();

    if (c < 16) {
        float s = fc_b1[tid];
        const float* wrow = fc_w1 + tid * AUXD;
        #pragma unroll 4
        for (int a = 0; a < AUXD; ++a) s += ylds[a] * wrow[a];
        float ap = fc_prelu[0];
        hl[tid] = s >= 0.f ? s : ap * s;
        __syncthreads();

        int o = c * 256 + tid;           // o = cout*64 + ci
        float t = fc_b2[o];
        const float* w2row = fc_w2 + o * HIDD;
        #pragma unroll 4
        for (int h = 0; h < HIDD; ++h) t += hl[h] * w2row[h];
        float mod = 1.f / (1.f + expf(-t));
        int cout = o >> 6, ci = o & 63;
        int cb = ci >> 3, cl = ci & 7;
        #pragma unroll
        for (int k = 0; k < 9; ++k) {
            float wv = weight[o * 9 + k];
            // 16B unit = ((n*9+k)*8 + cb)*64 + cout; halfword cl
            w_bf[((((n * 9 + k) * 8 + cb) * 64 + cout) << 3) + cl] = f2bf(mod * wv);
        }
    } else {
        float s = bias_b1[tid];
        const float* wrow = bias_w1 + tid * AUXD;
        #pragma unroll 4
        for (int a = 0; a < AUXD; ++a) s += ylds[a] * wrow[a];
        float ap = bias_prelu[0];
        hl[tid] = s >= 0.f ? s : ap * s;
        __syncthreads();
        if (tid < COUT) {
            float t = bias_b2[tid];
            const float* w2row = bias_w2 + tid * HIDD;
            #pragma unroll 4
            for (int h = 0; h < HIDD; ++h) t += hl[h] * w2row[h];
            bvec[n * COUT + tid] = t;
        }
    }
}

// ---------------- Kernel 2: conv ----------------
#define XISSUE(k, cc) { _Pragma("unroll") \
    for (int i = 0; i < 8; ++i) stg[k][i] = xr[k][(size_t)((cc) * 8 + i) * HWP]; }

#define XWRITE(k, buf) { float vm_ = vmr[k]; uint4 v_; \
    v_.x = cvtpk(stg[k][0], stg[k][1]); v_.y = cvtpk(stg[k][2], stg[k][3]); \
    v_.z = cvtpk(stg[k][4], stg[k][5]); v_.w = cvtpk(stg[k][6], stg[k][7]); \
    if (vm_ == 0.f) { v_.x = v_.y = v_.z = v_.w = 0u; } \
    *(uint4*)((buf) + (r0 + 2 * (k)) * XRW8 + (w + 1) * 16) = v_; }

__global__ __launch_bounds__(512, 2) void conv_kernel(
    const float* __restrict__ x, const unsigned short* __restrict__ w_bf,
    const float* __restrict__ bvec, float* __restrict__ out)
{
    __shared__ __align__(16) unsigned char smem[SMEMB6];

    const int bid = blockIdx.x;
    const int n = bid & 7;              // sample -> XCD (x/weights L2 locality)
    const int h0 = (bid >> 3) * 4;      // 4 output rows

    const int tid = threadIdx.x;
    const int lane = tid & 63;
    const int wave = tid >> 6;
    const int wr = wave >> 1;           // output row 0..3
    const int wh = wave & 1;            // 128-col half
    const int l5 = lane >> 5;           // K half (selects kidx of the pair)
    const int l31 = lane & 31;

    const int w = tid & 255;            // staging col
    const int r0 = tid >> 8;            // 0..1; stages rows r0, r0+2, r0+4

    // staging row pointers (clamped + zero mask at image edges)
    const float* xr[3];
    float vmr[3];
    #pragma unroll
    for (int k = 0; k < 3; ++k) {
        int r = r0 + 2 * k;
        int hin = h0 - 1 + r;
        bool val = (hin >= 0) && (hin < HH);
        xr[k] = x + (size_t)n * CIN * HWP + (size_t)(val ? hin : 0) * WW + w;
        vmr[k] = val ? 1.f : 0.f;
    }

    // ---- prologue: stage ALL weights (once) ----
    {
        const uint4* wsrc = (const uint4*)w_bf + (size_t)n * WUNITS;
        #pragma unroll
        for (int it = 0; it < 9; ++it) {
            int u = it * 512 + tid;
            *(uint4*)(smem + WOFF6 + (u << 4)) = wsrc[u];
        }
    }
    // zero halo entries (w-index 0 and 257): 2 bufs x 6 rows x 2 sides = 24
    if (tid < 24) {
        int buf = tid / 12, rem = tid % 12, rr = rem >> 1, side = rem & 1;
        uint4 z; z.x = z.y = z.z = z.w = 0u;
        *(uint4*)(smem + buf * XBUF6 + rr * XRW8 + (side ? 257 : 0) * 16) = z;
    }
    if (tid == 24) {  // zero A-pad unit
        uint4 z; z.x = z.y = z.z = z.w = 0u;
        *(uint4*)(smem + WOFF6 + (WUNITS << 4)) = z;
    }

    // staging registers (depth-1: one chunk in flight)
    float stg[3][8];

    // prologue: chunk 0 -> buf0
    XISSUE(0, 0); XWRITE(0, smem);
    XISSUE(1, 0); XWRITE(1, smem);
    XISSUE(2, 0); XWRITE(2, smem);

    // acc init = per-cout bias (D row = (reg&3) + 8*(reg>>2) + 4*l5)
    f32x16 acc[2][4];
    #pragma unroll
    for (int m = 0; m < 2; ++m) {
        #pragma unroll
        for (int reg = 0; reg < 16; ++reg)
            acc[m][0][reg] = bvec[n * COUT + m * 32 + (reg & 3) + 8 * (reg >> 2) + 4 * l5];
        #pragma unroll
        for (int j = 1; j < 4; ++j) acc[m][j] = acc[m][0];
    }

    asm volatile("s_waitcnt lgkmcnt(0)" ::: "memory");
    __builtin_amdgcn_s_barrier();

    #pragma unroll
    for (int c = 0; c < 8; ++c) {
        const int p = c & 1;
        const unsigned char* rbuf = smem + p * XBUF6;
        unsigned char* nx = smem + (p ^ 1) * XBUF6;
        const bool more = (c < 7);
        const int ncc = c + 1;

        #pragma unroll
        for (int s = 0; s < 5; ++s) {
            const int ka = 2 * s;                     // 0,2,4,6,8
            const int kb = (s == 4) ? 8 : 2 * s + 1;  // pad pair at s=4
            const bool solo = (s == 4);
            const int khA = ka / 3, kwA = ka % 3;
            const int khB = kb / 3, kwB = kb % 3;
            const int kh = l5 ? khB : khA;
            const int kw = l5 ? kwB : kwA;

            // A-frags: lane holds A[cout = m*32+l31][k = 8*l5 + j]
            int au = (solo && l5) ? WUNITS : ((l5 ? kb : ka) * 8 + c) * 64 + l31;
            int am = (solo && l5) ? 0 : 32;
            bf16x8 aA = *(const bf16x8*)(smem + WOFF6 + (au << 4));
            bf16x8 aB = *(const bf16x8*)(smem + WOFF6 + ((au + am) << 4));

            // B-frags: lane holds B[k][col = l31] = x[wr+kh][col+kw]
            const unsigned char* bb = rbuf + (wr + kh) * XRW8;
            bf16x8 bfr[4];
            #pragma unroll
            for (int j = 0; j < 4; ++j)
                bfr[j] = *(const bf16x8*)(bb + ((wh * 128 + j * 32 + l31 + kw) << 4));

            // depth-1 staging: issue chunk c+1 early, write it late
            if (more) {
                if (s == 0)      { XISSUE(0, ncc); }
                else if (s == 1) { XISSUE(1, ncc); }
                else if (s == 2) { XISSUE(2, ncc); }
                else if (s == 3) { XWRITE(0, nx); XWRITE(1, nx); }
                else             { XWRITE(2, nx); }
            }

            __builtin_amdgcn_s_setprio(1);
            #pragma unroll
            for (int j = 0; j < 4; ++j) {
                acc[0][j] = __builtin_amdgcn_mfma_f32_32x32x16_bf16(aA, bfr[j], acc[0][j], 0, 0, 0);
                acc[1][j] = __builtin_amdgcn_mfma_f32_32x32x16_bf16(aB, bfr[j], acc[1][j], 0, 0, 0);
            }
            __builtin_amdgcn_s_setprio(0);
        }

        // end-of-chunk: drain LDS ops only; global loads stay outstanding
        asm volatile("s_waitcnt lgkmcnt(0)" ::: "memory");
        __builtin_amdgcn_s_barrier();
    }

    // epilogue: D col = l31, row = (reg&3) + 8*(reg>>2) + 4*l5
    // NONTEMPORAL: out is write-once/never-read; bypass L2 to keep x/weights hot.
    const int hout = h0 + wr;
    float* ob = out + ((size_t)n * COUT * HH + hout) * WW;
    #pragma unroll
    for (int m = 0; m < 2; ++m) {
        #pragma unroll
        for (int j = 0; j < 4; ++j) {
            int colb = wh * 128 + j * 32 + l31;
            #pragma unroll
            for (int reg = 0; reg < 16; ++reg) {
                int cout = m * 32 + (reg & 3) + 8 * (reg >> 2) + 4 * l5;
                __builtin_nontemporal_store(acc[m][j][reg],
                                            ob + (size_t)cout * HWP + colb);
            }
        }
    }
}

extern "C" void kernel_launch(void* const* d_in, const int* in_sizes, int n_in,
                              void* d_out, int out_size, void* d_ws, size_t ws_size,
                              hipStream_t stream) {
    const float* x          = (const float*)d_in[0];
    const float* y          = (const float*)d_in[1];
    const float* weight     = (const float*)d_in[2];
    const float* fc_w1      = (const float*)d_in[3];
    const float* fc_b1      = (const float*)d_in[4];
    const float* fc_prelu   = (const float*)d_in[5];
    const float* fc_w2      = (const float*)d_in[6];
    const float* fc_b2      = (const float*)d_in[7];
    const float* bias_w1    = (const float*)d_in[8];
    const float* bias_b1    = (const float*)d_in[9];
    const float* bias_prelu = (const float*)d_in[10];
    const float* bias_w2    = (const float*)d_in[11];
    const float* bias_b2    = (const float*)d_in[12];
    float* out = (float*)d_out;

    unsigned short* w_bf = (unsigned short*)d_ws;                       // 589824 B
    float* bvec = (float*)((char*)d_ws + (size_t)NB * 9 * 64 * 64 * 2); // 2048 B

    hipLaunchKernelGGL(mlp_kernel, dim3(17, 8), dim3(256), 0, stream,
                       y, weight, fc_w1, fc_b1, fc_prelu, fc_w2, fc_b2,
                       bias_w1, bias_b1, bias_prelu, bias_w2, bias_b2, w_bf, bvec);
    hipLaunchKernelGGL(conv_kernel, dim3(512), dim3(512), 0, stream,
                       x, w_bf, bvec, out);
}

// Round 19
// 82.771 us; speedup vs baseline: 1.0440x; 1.0440x over previous
//
#include <hip/hip_runtime.h>
#include <hip/hip_bf16.h>

// ModConv2d: per-sample modulated 3x3 conv (N=8, C=64->64, 256x256) + MLPs.
// Kernel 1: MLPs -> w_bf[n][kidx][cb][cout][8ci] (bf16, A-frag 16B units) + bias.
// Kernel 2 (R19 = R17 + persistent row-group pair): implicit-GEMM conv,
//   builtin mfma_f32_32x32x16_bf16, 8-ci chunks, kidx-pair K=16 steps
//   (5/chunk, pad pair s=4 reads zero A-slot).
//   Grid 256 (1 block/CU, single generation). Block loops pg=0,1 over two
//   4-row groups (8-row band): weights staged ONCE per CU (-50% weight
//   fabric traffic, -1 prologue). Inner body is R17-verbatim (82.8us best):
//   512 thr (8 waves), wave (wr, wh) = row x 128-col half, acc[2][4] =
//   128 AGPR, r/m = 0.75; x LDS [6 rows][258][16B] dbuf + weights = 123.3 KB;
//   staging thread owns col w, rows {r0,r0+2,r0+4}, depth-1 ISSUE s0-2 /
//   WRITE s3-4; raw s_barrier + lgkmcnt(0); setprio on MFMA cluster; cvtpk.
//   pg boundary: vmcnt(0) drain (pg0 stores would inflate pg1's counted
//   vmcnt waits - R12 lesson) + barrier.

typedef short bf16x8 __attribute__((ext_vector_type(8)));
typedef float f32x16 __attribute__((ext_vector_type(16)));

#define NB 8
#define CIN 64
#define COUT 64
#define HH 256
#define WW 256
#define HWP (HH * WW)
#define AUXD 128
#define HIDD 256

#define XRW8 (258 * 16)            // 4128 B: one staged row-plane (8 ci)
#define XBUF6 (6 * XRW8)           // 24768 B per buffer
#define WOFF6 (2 * XBUF6)          // 49536
#define WUNITS (9 * 8 * 64)        // 4608 16B units
#define SMEMB6 (WOFF6 + (WUNITS + 1) * 16)  // 123280

__device__ __forceinline__ unsigned short f2bf(float f) {
    unsigned u = __builtin_bit_cast(unsigned, f);
    u += 0x7FFFu + ((u >> 16) & 1u);   // RNE
    return (unsigned short)(u >> 16);
}

__device__ __forceinline__ unsigned cvtpk(float a, float b) {
    unsigned r;  // r[15:0] = bf16(a), r[31:16] = bf16(b)
    asm volatile("v_cvt_pk_bf16_f32 %0, %1, %2" : "=v"(r) : "v"(a), "v"(b));
    return r;
}

// ---------------- Kernel 1: MLPs ----------------
__global__ __launch_bounds__(256) void mlp_kernel(
    const float* __restrict__ y, const float* __restrict__ weight,
    const float* __restrict__ fc_w1, const float* __restrict__ fc_b1,
    const float* __restrict__ fc_prelu,
    const float* __restrict__ fc_w2, const float* __restrict__ fc_b2,
    const float* __restrict__ bias_w1, const float* __restrict__ bias_b1,
    const float* __restrict__ bias_prelu,
    const float* __restrict__ bias_w2, const float* __restrict__ bias_b2,
    unsigned short* __restrict__ w_bf, float* __restrict__ bvec)
{
    const int n = blockIdx.y;
    const int c = blockIdx.x;
    const int tid = threadIdx.x;
    __shared__ float ylds[AUXD];
    __shared__ float hl[HIDD];
    if (tid < AUXD) ylds[tid] = y[n * AUXD + tid];
    __syncthreads();

    if (c < 16) {
        float s = fc_b1[tid];
        const float* wrow = fc_w1 + tid * AUXD;
        #pragma unroll 4
        for (int a = 0; a < AUXD; ++a) s += ylds[a] * wrow[a];
        float ap = fc_prelu[0];
        hl[tid] = s >= 0.f ? s : ap * s;
        __syncthreads();

        int o = c * 256 + tid;           // o = cout*64 + ci
        float t = fc_b2[o];
        const float* w2row = fc_w2 + o * HIDD;
        #pragma unroll 4
        for (int h = 0; h < HIDD; ++h) t += hl[h] * w2row[h];
        float mod = 1.f / (1.f + expf(-t));
        int cout = o >> 6, ci = o & 63;
        int cb = ci >> 3, cl = ci & 7;
        #pragma unroll
        for (int k = 0; k < 9; ++k) {
            float wv = weight[o * 9 + k];
            // 16B unit = ((n*9+k)*8 + cb)*64 + cout; halfword cl
            w_bf[((((n * 9 + k) * 8 + cb) * 64 + cout) << 3) + cl] = f2bf(mod * wv);
        }
    } else {
        float s = bias_b1[tid];
        const float* wrow = bias_w1 + tid * AUXD;
        #pragma unroll 4
        for (int a = 0; a < AUXD; ++a) s += ylds[a] * wrow[a];
        float ap = bias_prelu[0];
        hl[tid] = s >= 0.f ? s : ap * s;
        __syncthreads();
        if (tid < COUT) {
            float t = bias_b2[tid];
            const float* w2row = bias_w2 + tid * HIDD;
            #pragma unroll 4
            for (int h = 0; h < HIDD; ++h) t += hl[h] * w2row[h];
            bvec[n * COUT + tid] = t;
        }
    }
}

// ---------------- Kernel 2: conv ----------------
#define XISSUE(k, cc) { _Pragma("unroll") \
    for (int i = 0; i < 8; ++i) stg[k][i] = xr[k][(size_t)((cc) * 8 + i) * HWP]; }

#define XWRITE(k, buf) { float vm_ = vmr[k]; uint4 v_; \
    v_.x = cvtpk(stg[k][0], stg[k][1]); v_.y = cvtpk(stg[k][2], stg[k][3]); \
    v_.z = cvtpk(stg[k][4], stg[k][5]); v_.w = cvtpk(stg[k][6], stg[k][7]); \
    if (vm_ == 0.f) { v_.x = v_.y = v_.z = v_.w = 0u; } \
    *(uint4*)((buf) + (r0 + 2 * (k)) * XRW8 + (w + 1) * 16) = v_; }

__global__ __launch_bounds__(512, 2) void conv_kernel(
    const float* __restrict__ x, const unsigned short* __restrict__ w_bf,
    const float* __restrict__ bvec, float* __restrict__ out)
{
    __shared__ __align__(16) unsigned char smem[SMEMB6];

    const int bid = blockIdx.x;
    const int n = bid & 7;              // sample -> XCD (x/weights L2 locality)
    const int hb = (bid >> 3) * 8;      // 8-row band; pg loop covers 2x4 rows

    const int tid = threadIdx.x;
    const int lane = tid & 63;
    const int wave = tid >> 6;
    const int wr = wave >> 1;           // output row 0..3 (within group)
    const int wh = wave & 1;            // 128-col half
    const int l5 = lane >> 5;           // K half (selects kidx of the pair)
    const int l31 = lane & 31;

    const int w = tid & 255;            // staging col
    const int r0 = tid >> 8;            // 0..1; stages rows r0, r0+2, r0+4

    // ---- prologue: stage ALL weights (once per CU) ----
    {
        const uint4* wsrc = (const uint4*)w_bf + (size_t)n * WUNITS;
        #pragma unroll
        for (int it = 0; it < 9; ++it) {
            int u = it * 512 + tid;
            *(uint4*)(smem + WOFF6 + (u << 4)) = wsrc[u];
        }
    }
    // zero halo entries (w-index 0 and 257): 2 bufs x 6 rows x 2 sides = 24
    if (tid < 24) {
        int buf = tid / 12, rem = tid % 12, rr = rem >> 1, side = rem & 1;
        uint4 z; z.x = z.y = z.z = z.w = 0u;
        *(uint4*)(smem + buf * XBUF6 + rr * XRW8 + (side ? 257 : 0) * 16) = z;
    }
    if (tid == 24) {  // zero A-pad unit
        uint4 z; z.x = z.y = z.z = z.w = 0u;
        *(uint4*)(smem + WOFF6 + (WUNITS << 4)) = z;
    }

    float stg[3][8];
    const float* xr[3];
    float vmr[3];

    for (int pg = 0; pg < 2; ++pg) {
        const int h0 = hb + pg * 4;

        // staging row pointers for this group (clamped + zero mask at edges)
        #pragma unroll
        for (int k = 0; k < 3; ++k) {
            int r = r0 + 2 * k;
            int hin = h0 - 1 + r;
            bool val = (hin >= 0) && (hin < HH);
            xr[k] = x + (size_t)n * CIN * HWP + (size_t)(val ? hin : 0) * WW + w;
            vmr[k] = val ? 1.f : 0.f;
        }

        // group prologue: chunk 0 -> buf0
        XISSUE(0, 0); XWRITE(0, smem);
        XISSUE(1, 0); XWRITE(1, smem);
        XISSUE(2, 0); XWRITE(2, smem);

        // acc init = per-cout bias (D row = (reg&3) + 8*(reg>>2) + 4*l5)
        f32x16 acc[2][4];
        #pragma unroll
        for (int m = 0; m < 2; ++m) {
            #pragma unroll
            for (int reg = 0; reg < 16; ++reg)
                acc[m][0][reg] = bvec[n * COUT + m * 32 + (reg & 3) + 8 * (reg >> 2) + 4 * l5];
            #pragma unroll
            for (int j = 1; j < 4; ++j) acc[m][j] = acc[m][0];
        }

        asm volatile("s_waitcnt lgkmcnt(0)" ::: "memory");
        __builtin_amdgcn_s_barrier();

        #pragma unroll
        for (int c = 0; c < 8; ++c) {
            const int p = c & 1;
            const unsigned char* rbuf = smem + p * XBUF6;
            unsigned char* nx = smem + (p ^ 1) * XBUF6;
            const bool more = (c < 7);
            const int ncc = c + 1;

            #pragma unroll
            for (int s = 0; s < 5; ++s) {
                const int ka = 2 * s;                     // 0,2,4,6,8
                const int kb = (s == 4) ? 8 : 2 * s + 1;  // pad pair at s=4
                const bool solo = (s == 4);
                const int khA = ka / 3, kwA = ka % 3;
                const int khB = kb / 3, kwB = kb % 3;
                const int kh = l5 ? khB : khA;
                const int kw = l5 ? kwB : kwA;

                // A-frags: lane holds A[cout = m*32+l31][k = 8*l5 + j]
                int au = (solo && l5) ? WUNITS : ((l5 ? kb : ka) * 8 + c) * 64 + l31;
                int am = (solo && l5) ? 0 : 32;
                bf16x8 aA = *(const bf16x8*)(smem + WOFF6 + (au << 4));
                bf16x8 aB = *(const bf16x8*)(smem + WOFF6 + ((au + am) << 4));

                // B-frags: lane holds B[k][col = l31] = x[wr+kh][col+kw]
                const unsigned char* bb = rbuf + (wr + kh) * XRW8;
                bf16x8 bfr[4];
                #pragma unroll
                for (int j = 0; j < 4; ++j)
                    bfr[j] = *(const bf16x8*)(bb + ((wh * 128 + j * 32 + l31 + kw) << 4));

                // depth-1 staging: issue chunk c+1 early, write it late
                if (more) {
                    if (s == 0)      { XISSUE(0, ncc); }
                    else if (s == 1) { XISSUE(1, ncc); }
                    else if (s == 2) { XISSUE(2, ncc); }
                    else if (s == 3) { XWRITE(0, nx); XWRITE(1, nx); }
                    else             { XWRITE(2, nx); }
                }

                __builtin_amdgcn_s_setprio(1);
                #pragma unroll
                for (int j = 0; j < 4; ++j) {
                    acc[0][j] = __builtin_amdgcn_mfma_f32_32x32x16_bf16(aA, bfr[j], acc[0][j], 0, 0, 0);
                    acc[1][j] = __builtin_amdgcn_mfma_f32_32x32x16_bf16(aB, bfr[j], acc[1][j], 0, 0, 0);
                }
                __builtin_amdgcn_s_setprio(0);
            }

            // end-of-chunk: drain LDS ops only; global loads stay outstanding
            asm volatile("s_waitcnt lgkmcnt(0)" ::: "memory");
            __builtin_amdgcn_s_barrier();
        }

        // epilogue for this group: D col = l31, row = (reg&3)+8*(reg>>2)+4*l5
        {
            const int hout = h0 + wr;
            float* ob = out + ((size_t)n * COUT * HH + hout) * WW;
            #pragma unroll
            for (int m = 0; m < 2; ++m) {
                #pragma unroll
                for (int j = 0; j < 4; ++j) {
                    int colb = wh * 128 + j * 32 + l31;
                    #pragma unroll
                    for (int reg = 0; reg < 16; ++reg) {
                        int cout = m * 32 + (reg & 3) + 8 * (reg >> 2) + 4 * l5;
                        ob[(size_t)cout * HWP + colb] = acc[m][j][reg];
                    }
                }
            }
        }

        if (pg == 0) {
            // drain the store queue so pg1's counted vmcnt waits aren't
            // inflated by 128 outstanding stores (R12 lesson), and make the
            // x buffers safely rewritable.
            asm volatile("s_waitcnt vmcnt(0) lgkmcnt(0)" ::: "memory");
            __builtin_amdgcn_s_barrier();
        }
    }
}

extern "C" void kernel_launch(void* const* d_in, const int* in_sizes, int n_in,
                              void* d_out, int out_size, void* d_ws, size_t ws_size,
                              hipStream_t stream) {
    const float* x          = (const float*)d_in[0];
    const float* y          = (const float*)d_in[1];
    const float* weight     = (const float*)d_in[2];
    const float* fc_w1      = (const float*)d_in[3];
    const float* fc_b1      = (const float*)d_in[4];
    const float* fc_prelu   = (const float*)d_in[5];
    const float* fc_w2      = (const float*)d_in[6];
    const float* fc_b2      = (const float*)d_in[7];
    const float* bias_w1    = (const float*)d_in[8];
    const float* bias_b1    = (const float*)d_in[9];
    const float* bias_prelu = (const float*)d_in[10];
    const float* bias_w2    = (const float*)d_in[11];
    const float* bias_b2    = (const float*)d_in[12];
    float* out = (float*)d_out;

    unsigned short* w_bf = (unsigned short*)d_ws;                       // 589824 B
    float* bvec = (float*)((char*)d_ws + (size_t)NB * 9 * 64 * 64 * 2); // 2048 B

    hipLaunchKernelGGL(mlp_kernel, dim3(17, 8), dim3(256), 0, stream,
                       y, weight, fc_w1, fc_b1, fc_prelu, fc_w2, fc_b2,
                       bias_w1, bias_b1, bias_prelu, bias_w2, bias_b2, w_bf, bvec);
    hipLaunchKernelGGL(conv_kernel, dim3(256), dim3(512), 0, stream,
                       x, w_bf, bvec, out);
}